// Round 1
// baseline (107.414 us; speedup 1.0000x reference)
//
#include <hip/hip_runtime.h>
#include <hip/hip_bf16.h>

// Fully fused QuanvolutionHybridClassifier forward.
//
// Math note: the 4-qubit circuit (RY(d_w) encode, RY(q0..q3) per wire,
// CNOT(0,1), CNOT(2,3), RY(q4) on wire1, CNOT(1,2), PauliZ readout)
// collapses analytically. With a_w = d_w + q_w:
//   z0 = cos a0
//   z1 = cos q4 * cos a0 * cos a1 - sin q4 * sin a1
//   z2 = z1 * cos a2
//   z3 = cos a2 * cos a3
// (Heisenberg evolution of each Z_w through the fixed Clifford+RY tail;
// product-state expectations factorize.)

#define SPB 8          // samples per block
#define THREADS 256
#define NCLS 10
#define FEAT 1568      // 784 flat + 784 quantum

__global__ __launch_bounds__(THREADS, 3)
void quanv_fused_kernel(const float* __restrict__ x,        // [B,1,28,28]
                        const float* __restrict__ conv_w,   // [4,1,2,2]
                        const float* __restrict__ conv_b,   // [4]
                        const float* __restrict__ q_params, // [5]
                        const float* __restrict__ lin_w,    // [10,1568]
                        const float* __restrict__ lin_b,    // [10]
                        float* __restrict__ out)            // [B,10]
{
    __shared__ float comb[SPB][FEAT];

    const int tid = threadIdx.x;
    const int n0  = blockIdx.x * SPB;

    // ---- uniform small params (L1-broadcast loads) ----
    float W[4][4], Bc[4];
    #pragma unroll
    for (int c = 0; c < 4; ++c) {
        #pragma unroll
        for (int k = 0; k < 4; ++k) W[c][k] = conv_w[c * 4 + k];
        Bc[c] = conv_b[c];
    }
    const float qp0 = q_params[0], qp1 = q_params[1];
    const float qp2 = q_params[2], qp3 = q_params[3];
    const float q4  = q_params[4];
    const float cq4 = cosf(q4), sq4 = sinf(q4);

    // ---- Step 1: conv (2x2, stride 2, 4 ch) -> flat region comb[s][0..783]
    // flat layout: c*196 + h*14 + w  (channel-major, matches feats.reshape)
    for (int p = tid; p < SPB * 196; p += THREADS) {
        const int s = p / 196, r = p % 196;
        const int h = r / 14, w = r % 14;
        const float* xp = x + (size_t)(n0 + s) * 784 + (2 * h) * 28 + 2 * w;
        const float x00 = xp[0], x01 = xp[1], x10 = xp[28], x11 = xp[29];
        #pragma unroll
        for (int c = 0; c < 4; ++c) {
            comb[s][c * 196 + r] =
                fmaf(x00, W[c][0], fmaf(x01, W[c][1],
                fmaf(x10, W[c][2], fmaf(x11, W[c][3], Bc[c]))));
        }
    }
    __syncthreads();

    // ---- Step 2: quantum features on 2x2 patches of the 28x28 *view* of flat
    // patch(i,j) elems: flat[28*(2i+a) + 2j+b]; q[r*4+e] = z_e, r = i*14+j
    for (int p = tid; p < SPB * 196; p += THREADS) {
        const int s = p / 196, r = p % 196;
        const int i = r / 14, j = r % 14;
        const int base = 56 * i + 2 * j;
        const float d0 = comb[s][base],      d1 = comb[s][base + 1];
        const float d2 = comb[s][base + 28], d3 = comb[s][base + 29];
        const float a0 = d0 + qp0, a1 = d1 + qp1;
        const float a2 = d2 + qp2, a3 = d3 + qp3;
        const float c0 = cosf(a0);
        const float c1 = cosf(a1), s1 = sinf(a1);
        const float c2 = cosf(a2), c3 = cosf(a3);
        const float z0 = c0;
        const float z1 = cq4 * c0 * c1 - sq4 * s1;
        const float z2 = z1 * c2;
        const float z3 = c2 * c3;
        *reinterpret_cast<float4*>(&comb[s][784 + r * 4]) =
            make_float4(z0, z1, z2, z3);
    }
    __syncthreads();

    // ---- Step 3: linear [1568]x[10] + log_softmax. Wave w owns samples
    // (2w, 2w+1). Coalesced lin_w reads (L2-resident), LDS stride-1 reads.
    const int wave = tid >> 6, lane = tid & 63;
    const int s0 = 2 * wave, s1 = s0 + 1;

    float acc0[NCLS], acc1[NCLS];
    #pragma unroll
    for (int c = 0; c < NCLS; ++c) { acc0[c] = 0.f; acc1[c] = 0.f; }

    for (int k = lane; k < FEAT; k += 64) {
        const float v0 = comb[s0][k];
        const float v1 = comb[s1][k];
        #pragma unroll
        for (int c = 0; c < NCLS; ++c) {
            const float lw = lin_w[c * FEAT + k];
            acc0[c] = fmaf(v0, lw, acc0[c]);
            acc1[c] = fmaf(v1, lw, acc1[c]);
        }
    }

    // butterfly reduce across the 64-lane wave (all lanes end with full sums)
    #pragma unroll
    for (int m = 1; m < 64; m <<= 1) {
        #pragma unroll
        for (int c = 0; c < NCLS; ++c) {
            acc0[c] += __shfl_xor(acc0[c], m, 64);
            acc1[c] += __shfl_xor(acc1[c], m, 64);
        }
    }

    if (lane == 0) {
        float lg[NCLS], mx = -1e30f;
        #pragma unroll
        for (int c = 0; c < NCLS; ++c) {
            lg[c] = acc0[c] + lin_b[c];
            mx = fmaxf(mx, lg[c]);
        }
        float sum = 0.f;
        #pragma unroll
        for (int c = 0; c < NCLS; ++c) sum += expf(lg[c] - mx);
        const float lse = mx + logf(sum);
        float* o = out + (size_t)(n0 + s0) * NCLS;
        #pragma unroll
        for (int c = 0; c < NCLS; ++c) o[c] = lg[c] - lse;
    } else if (lane == 1) {
        float lg[NCLS], mx = -1e30f;
        #pragma unroll
        for (int c = 0; c < NCLS; ++c) {
            lg[c] = acc1[c] + lin_b[c];
            mx = fmaxf(mx, lg[c]);
        }
        float sum = 0.f;
        #pragma unroll
        for (int c = 0; c < NCLS; ++c) sum += expf(lg[c] - mx);
        const float lse = mx + logf(sum);
        float* o = out + (size_t)(n0 + s1) * NCLS;
        #pragma unroll
        for (int c = 0; c < NCLS; ++c) o[c] = lg[c] - lse;
    }
}

extern "C" void kernel_launch(void* const* d_in, const int* in_sizes, int n_in,
                              void* d_out, int out_size, void* d_ws, size_t ws_size,
                              hipStream_t stream) {
    const float* x        = (const float*)d_in[0];
    const float* conv_w   = (const float*)d_in[1];
    const float* conv_b   = (const float*)d_in[2];
    const float* q_params = (const float*)d_in[3];
    const float* lin_w    = (const float*)d_in[4];
    const float* lin_b    = (const float*)d_in[5];
    float* out = (float*)d_out;

    const int B = in_sizes[0] / 784;   // 8192
    const int nblocks = B / SPB;       // 1024

    quanv_fused_kernel<<<nblocks, THREADS, 0, stream>>>(
        x, conv_w, conv_b, q_params, lin_w, lin_b, out);
}

// Round 5
// 102.984 us; speedup vs baseline: 1.0430x; 1.0430x over previous
//
#include <hip/hip_runtime.h>
#include <hip/hip_bf16.h>

// Fully fused QuanvolutionHybridClassifier forward (round-2 design,
// fourth submission — rounds 2-4 all failed on GPU acquisition; no
// counters yet for this design, so it is resubmitted unchanged).
//
// Circuit collapse (verified passing in round 1): with a_w = d_w + q_w,
//   z0 = cos a0
//   z1 = cos q4 * cos a0 * cos a1 - sq4 * sin a1   (cq4=cos q4, sq4=sin q4)
//   z2 = z1 * cos a2
//   z3 = cos a2 * cos a3
//
// Changes vs measured round-1 (latency/occupancy-bound, 22% occ, 31% VALU):
//  - SPB 8 -> 4: LDS 50KB -> 25KB, 3 -> 6 blocks/CU (12 -> 24 waves/CU)
//  - __cosf/__sinf native transcendentals (inputs |a| small, err ~1e-6)
//  - step-3 float4 loads for both LDS feature reads and lin_w (L2-resident)
//  - step-1: 2 outputs/thread via 2x float4 coalesced x loads

#define SPB 4          // samples per block
#define THREADS 256
#define NCLS 10
#define FEAT 1568      // 784 flat + 784 quantum

__global__ __launch_bounds__(THREADS, 6)
void quanv_fused_kernel(const float* __restrict__ x,        // [B,1,28,28]
                        const float* __restrict__ conv_w,   // [4,1,2,2]
                        const float* __restrict__ conv_b,   // [4]
                        const float* __restrict__ q_params, // [5]
                        const float* __restrict__ lin_w,    // [10,1568]
                        const float* __restrict__ lin_b,    // [10]
                        float* __restrict__ out)            // [B,10]
{
    __shared__ float comb[SPB][FEAT];

    const int tid = threadIdx.x;
    const int n0  = blockIdx.x * SPB;

    // ---- uniform small params (L1-broadcast loads) ----
    float W[4][4], Bc[4];
    #pragma unroll
    for (int c = 0; c < 4; ++c) {
        #pragma unroll
        for (int k = 0; k < 4; ++k) W[c][k] = conv_w[c * 4 + k];
        Bc[c] = conv_b[c];
    }
    const float qp0 = q_params[0], qp1 = q_params[1];
    const float qp2 = q_params[2], qp3 = q_params[3];
    const float q4  = q_params[4];
    const float cq4 = __cosf(q4), sq4 = __sinf(q4);

    // ---- Step 1: conv (2x2, stride 2, 4 ch) -> flat region comb[s][0..783]
    // 2 adjacent outputs per item: item t = (h, wp), outputs (h,2wp),(h,2wp+1)
    // covered by two float4 row loads. flat layout: c*196 + h*14 + w.
    for (int p = tid; p < SPB * 14 * 7; p += THREADS) {
        const int s = p / 98, t = p % 98;
        const int h = t / 7, wp = t % 7;
        const float* xp = x + (size_t)(n0 + s) * 784 + 56 * h + 4 * wp;
        const float4 r0 = *reinterpret_cast<const float4*>(xp);
        const float4 r1 = *reinterpret_cast<const float4*>(xp + 28);
        const int r = h * 14 + 2 * wp;
        #pragma unroll
        for (int c = 0; c < 4; ++c) {
            comb[s][c * 196 + r] =
                fmaf(r0.x, W[c][0], fmaf(r0.y, W[c][1],
                fmaf(r1.x, W[c][2], fmaf(r1.y, W[c][3], Bc[c]))));
            comb[s][c * 196 + r + 1] =
                fmaf(r0.z, W[c][0], fmaf(r0.w, W[c][1],
                fmaf(r1.z, W[c][2], fmaf(r1.w, W[c][3], Bc[c]))));
        }
    }
    __syncthreads();

    // ---- Step 2: quantum features on 2x2 patches of the 28x28 *view* of flat
    for (int p = tid; p < SPB * 196; p += THREADS) {
        const int s = p / 196, r = p % 196;
        const int i = r / 14, j = r % 14;
        const int base = 56 * i + 2 * j;
        const float2 d01 = *reinterpret_cast<const float2*>(&comb[s][base]);
        const float2 d23 = *reinterpret_cast<const float2*>(&comb[s][base + 28]);
        const float a0 = d01.x + qp0, a1 = d01.y + qp1;
        const float a2 = d23.x + qp2, a3 = d23.y + qp3;
        const float c0 = __cosf(a0);
        const float c1 = __cosf(a1), s1 = __sinf(a1);
        const float c2 = __cosf(a2), c3 = __cosf(a3);
        const float z0 = c0;
        const float z1 = cq4 * c0 * c1 - sq4 * s1;
        const float z2 = z1 * c2;
        const float z3 = c2 * c3;
        *reinterpret_cast<float4*>(&comb[s][784 + r * 4]) =
            make_float4(z0, z1, z2, z3);
    }
    __syncthreads();

    // ---- Step 3: linear [1568]x[10] + log_softmax. One sample per wave.
    const int wave = tid >> 6, lane = tid & 63;
    const int s = wave;

    float acc[NCLS];
    #pragma unroll
    for (int c = 0; c < NCLS; ++c) acc[c] = 0.f;

    // 6 full float4 strips: k = kb*256 + lane*4, covers [0,1536)
    #pragma unroll
    for (int kb = 0; kb < 6; ++kb) {
        const int k = kb * 256 + lane * 4;
        const float4 v = *reinterpret_cast<const float4*>(&comb[s][k]);
        #pragma unroll
        for (int c = 0; c < NCLS; ++c) {
            const float4 w4 = *reinterpret_cast<const float4*>(&lin_w[c * FEAT + k]);
            acc[c] = fmaf(v.x, w4.x, fmaf(v.y, w4.y,
                     fmaf(v.z, w4.z, fmaf(v.w, w4.w, acc[c]))));
        }
    }
    // tail [1536,1568): 32 scalars, lanes 0..31
    if (lane < 32) {
        const int k = 1536 + lane;
        const float v = comb[s][k];
        #pragma unroll
        for (int c = 0; c < NCLS; ++c)
            acc[c] = fmaf(v, lin_w[c * FEAT + k], acc[c]);
    }

    // butterfly reduce across the 64-lane wave
    #pragma unroll
    for (int m = 1; m < 64; m <<= 1) {
        #pragma unroll
        for (int c = 0; c < NCLS; ++c)
            acc[c] += __shfl_xor(acc[c], m, 64);
    }

    if (lane == 0) {
        float lg[NCLS], mx = -1e30f;
        #pragma unroll
        for (int c = 0; c < NCLS; ++c) {
            lg[c] = acc[c] + lin_b[c];
            mx = fmaxf(mx, lg[c]);
        }
        float sum = 0.f;
        #pragma unroll
        for (int c = 0; c < NCLS; ++c) sum += __expf(lg[c] - mx);
        const float lse = mx + __logf(sum);
        float* o = out + (size_t)(n0 + s) * NCLS;
        #pragma unroll
        for (int c = 0; c < NCLS; ++c) o[c] = lg[c] - lse;
    }
}

extern "C" void kernel_launch(void* const* d_in, const int* in_sizes, int n_in,
                              void* d_out, int out_size, void* d_ws, size_t ws_size,
                              hipStream_t stream) {
    const float* x        = (const float*)d_in[0];
    const float* conv_w   = (const float*)d_in[1];
    const float* conv_b   = (const float*)d_in[2];
    const float* q_params = (const float*)d_in[3];
    const float* lin_w    = (const float*)d_in[4];
    const float* lin_b    = (const float*)d_in[5];
    float* out = (float*)d_out;

    const int B = in_sizes[0] / 784;   // 8192
    const int nblocks = B / SPB;       // 2048

    quanv_fused_kernel<<<nblocks, THREADS, 0, stream>>>(
        x, conv_w, conv_b, q_params, lin_w, lin_b, out);
}

// Round 6
// 101.065 us; speedup vs baseline: 1.0628x; 1.0190x over previous
//
#include <hip/hip_runtime.h>
#include <hip/hip_bf16.h>

// Fully fused QuanvolutionHybridClassifier forward (round 6).
//
// Circuit collapse (verified): with a_w = d_w + q_w,
//   z0 = cos a0
//   z1 = cos q4 * cos a0 * cos a1 - sin q4 * sin a1
//   z2 = z1 * cos a2
//   z3 = cos a2 * cos a3
//
// Round-6 change vs round-2 design (kernel est. ~40 us, lin_w L1 traffic
// 513 MB suspected dominant): step 3 restructured so each wave handles
// 2 samples x half of K (wave = (pair, K-half)). Halves per-wave lin_w
// reads (31 KB vs 62.7 KB; total 257 MB), doubles FMA per loaded byte.
// Partials combined via small LDS array; 4-thread log_softmax epilogue.
// Steps 1-2 / SPB=4 / 25KB LDS / grid 2048 unchanged for attribution.

#define SPB 4          // samples per block
#define THREADS 256
#define NCLS 10
#define FEAT 1568      // 784 flat + 784 quantum

__global__ __launch_bounds__(THREADS, 6)
void quanv_fused_kernel(const float* __restrict__ x,        // [B,1,28,28]
                        const float* __restrict__ conv_w,   // [4,1,2,2]
                        const float* __restrict__ conv_b,   // [4]
                        const float* __restrict__ q_params, // [5]
                        const float* __restrict__ lin_w,    // [10,1568]
                        const float* __restrict__ lin_b,    // [10]
                        float* __restrict__ out)            // [B,10]
{
    __shared__ float comb[SPB][FEAT];
    __shared__ float part[SPB][2][12];   // [sample][K-half][class(+pad)]

    const int tid = threadIdx.x;
    const int n0  = blockIdx.x * SPB;

    // ---- uniform small params (L1-broadcast loads) ----
    float W[4][4], Bc[4];
    #pragma unroll
    for (int c = 0; c < 4; ++c) {
        #pragma unroll
        for (int k = 0; k < 4; ++k) W[c][k] = conv_w[c * 4 + k];
        Bc[c] = conv_b[c];
    }
    const float qp0 = q_params[0], qp1 = q_params[1];
    const float qp2 = q_params[2], qp3 = q_params[3];
    const float q4  = q_params[4];
    const float cq4 = __cosf(q4), sq4 = __sinf(q4);

    // ---- Step 1: conv (2x2, stride 2, 4 ch) -> flat region comb[s][0..783]
    // 2 adjacent outputs per item via two float4 row loads.
    // flat layout: c*196 + h*14 + w.
    for (int p = tid; p < SPB * 14 * 7; p += THREADS) {
        const int s = p / 98, t = p % 98;
        const int h = t / 7, wp = t % 7;
        const float* xp = x + (size_t)(n0 + s) * 784 + 56 * h + 4 * wp;
        const float4 r0 = *reinterpret_cast<const float4*>(xp);
        const float4 r1 = *reinterpret_cast<const float4*>(xp + 28);
        const int r = h * 14 + 2 * wp;
        #pragma unroll
        for (int c = 0; c < 4; ++c) {
            comb[s][c * 196 + r] =
                fmaf(r0.x, W[c][0], fmaf(r0.y, W[c][1],
                fmaf(r1.x, W[c][2], fmaf(r1.y, W[c][3], Bc[c]))));
            comb[s][c * 196 + r + 1] =
                fmaf(r0.z, W[c][0], fmaf(r0.w, W[c][1],
                fmaf(r1.z, W[c][2], fmaf(r1.w, W[c][3], Bc[c]))));
        }
    }
    __syncthreads();

    // ---- Step 2: quantum features on 2x2 patches of the 28x28 view of flat
    for (int p = tid; p < SPB * 196; p += THREADS) {
        const int s = p / 196, r = p % 196;
        const int i = r / 14, j = r % 14;
        const int base = 56 * i + 2 * j;
        const float2 d01 = *reinterpret_cast<const float2*>(&comb[s][base]);
        const float2 d23 = *reinterpret_cast<const float2*>(&comb[s][base + 28]);
        const float a0 = d01.x + qp0, a1 = d01.y + qp1;
        const float a2 = d23.x + qp2, a3 = d23.y + qp3;
        const float c0 = __cosf(a0);
        const float c1 = __cosf(a1), s1 = __sinf(a1);
        const float c2 = __cosf(a2), c3 = __cosf(a3);
        const float z0 = c0;
        const float z1 = cq4 * c0 * c1 - sq4 * s1;
        const float z2 = z1 * c2;
        const float z3 = c2 * c3;
        *reinterpret_cast<float4*>(&comb[s][784 + r * 4]) =
            make_float4(z0, z1, z2, z3);
    }
    __syncthreads();

    // ---- Step 3: linear [1568]x[10] + log_softmax.
    // Wave w = (pair p, K-half h): samples {2p, 2p+1}, K in [784h, 784h+784).
    const int wave = tid >> 6, lane = tid & 63;
    const int pr = wave & 1;
    const int h  = wave >> 1;
    const int s0 = 2 * pr, s1 = s0 + 1;
    const int kbase = h * 784;

    float acc0[NCLS], acc1[NCLS];
    #pragma unroll
    for (int c = 0; c < NCLS; ++c) { acc0[c] = 0.f; acc1[c] = 0.f; }

    // 3 full float4 strips of 256 floats: covers [kbase, kbase+768)
    #pragma unroll
    for (int kb = 0; kb < 3; ++kb) {
        const int k = kbase + kb * 256 + lane * 4;
        const float4 v0 = *reinterpret_cast<const float4*>(&comb[s0][k]);
        const float4 v1 = *reinterpret_cast<const float4*>(&comb[s1][k]);
        #pragma unroll
        for (int c = 0; c < NCLS; ++c) {
            const float4 w4 = *reinterpret_cast<const float4*>(&lin_w[c * FEAT + k]);
            acc0[c] = fmaf(v0.x, w4.x, fmaf(v0.y, w4.y,
                      fmaf(v0.z, w4.z, fmaf(v0.w, w4.w, acc0[c]))));
            acc1[c] = fmaf(v1.x, w4.x, fmaf(v1.y, w4.y,
                      fmaf(v1.z, w4.z, fmaf(v1.w, w4.w, acc1[c]))));
        }
    }
    // tail [kbase+768, kbase+784): 16 scalars, lanes 0..15
    if (lane < 16) {
        const int k = kbase + 768 + lane;
        const float v0 = comb[s0][k];
        const float v1 = comb[s1][k];
        #pragma unroll
        for (int c = 0; c < NCLS; ++c) {
            const float w = lin_w[c * FEAT + k];
            acc0[c] = fmaf(v0, w, acc0[c]);
            acc1[c] = fmaf(v1, w, acc1[c]);
        }
    }

    // butterfly reduce across the 64-lane wave
    #pragma unroll
    for (int m = 1; m < 64; m <<= 1) {
        #pragma unroll
        for (int c = 0; c < NCLS; ++c) {
            acc0[c] += __shfl_xor(acc0[c], m, 64);
            acc1[c] += __shfl_xor(acc1[c], m, 64);
        }
    }

    if (lane == 0) {
        #pragma unroll
        for (int c = 0; c < NCLS; ++c) {
            part[s0][h][c] = acc0[c];
            part[s1][h][c] = acc1[c];
        }
    }
    __syncthreads();

    // ---- Epilogue: one thread per sample combines K-halves + log_softmax
    if (tid < SPB) {
        const int s = tid;
        float lg[NCLS], mx = -1e30f;
        #pragma unroll
        for (int c = 0; c < NCLS; ++c) {
            lg[c] = part[s][0][c] + part[s][1][c] + lin_b[c];
            mx = fmaxf(mx, lg[c]);
        }
        float sum = 0.f;
        #pragma unroll
        for (int c = 0; c < NCLS; ++c) sum += __expf(lg[c] - mx);
        const float lse = mx + __logf(sum);
        float* o = out + (size_t)(n0 + s) * NCLS;
        #pragma unroll
        for (int c = 0; c < NCLS; ++c) o[c] = lg[c] - lse;
    }
}

extern "C" void kernel_launch(void* const* d_in, const int* in_sizes, int n_in,
                              void* d_out, int out_size, void* d_ws, size_t ws_size,
                              hipStream_t stream) {
    const float* x        = (const float*)d_in[0];
    const float* conv_w   = (const float*)d_in[1];
    const float* conv_b   = (const float*)d_in[2];
    const float* q_params = (const float*)d_in[3];
    const float* lin_w    = (const float*)d_in[4];
    const float* lin_b    = (const float*)d_in[5];
    float* out = (float*)d_out;

    const int B = in_sizes[0] / 784;   // 8192
    const int nblocks = B / SPB;       // 2048

    quanv_fused_kernel<<<nblocks, THREADS, 0, stream>>>(
        x, conv_w, conv_b, q_params, lin_w, lin_b, out);
}